// Round 7
// baseline (411.325 us; speedup 1.0000x reference)
//
#include <hip/hip_runtime.h>

#define N_NODES 50000
#define N_EDGES 1600000
#define IN_DIM 512
#define OUT_DIM 256

#define BM 64                  // 782 blocks = 3.05/CU (balanced); X read once (BN=256)
#define BN 256
#define BK 32
#define APAD 8                 // pad rows to 40 shorts = 80 B -> 2-way banks (free)
#define LDA (BK + APAD)

// ---- two-level counting sort geometry ----
#define RPB   128              // rows per bucket (rloc = 7 bits)
#define NBKT  391              // ceil(50000 / 128)
#define CHUNK 4096             // edges per scatter1 block
#define CAP   5120             // per-bucket tmp capacity (mean 4096, sigma 64 -> +16 sigma)

typedef unsigned int u32;
typedef unsigned short u16;
typedef short bf16x8 __attribute__((ext_vector_type(8)));
typedef float f32x4 __attribute__((ext_vector_type(4)));

__device__ __forceinline__ float bf_to_f(u16 u) { return __uint_as_float(((u32)u) << 16); }
__device__ __forceinline__ u16 f_to_bf(float f) {
    u32 u = __float_as_uint(f);
    u32 r = (u + 0x7fffu + ((u >> 16) & 1u)) >> 16;   // RNE
    return (u16)r;
}

// ---------------------------------------------------------------------------
// CSR build, two-level (verified).
// ---------------------------------------------------------------------------
__global__ __launch_bounds__(256) void zero_cur(int* __restrict__ cursor) {
    const int i = blockIdx.x * 256 + threadIdx.x;
    if (i < NBKT) cursor[i] = 0;
}

// edges -> bucket-major tmp (fixed CAP per bucket).  Edge packed as
// w0 = col | (rloc<<16) | (bkt<<23), w1 = val bits (col < 65536, rloc < 128).
__global__ __launch_bounds__(256) void scatter1(const int* __restrict__ er,
                                                const int* __restrict__ ec,
                                                const float* __restrict__ ev,
                                                int* __restrict__ cursor,
                                                int2* __restrict__ tmp) {
    __shared__ int  hcnt[NBKT];
    __shared__ int  loff[NBKT];
    __shared__ int  gbase[NBKT];
    __shared__ int  sc[512];
    __shared__ int2 estage[CHUNK];   // 32 KB
    __shared__ u16  bslot[CHUNK];    // 8 KB

    const int t = threadIdx.x;
    const int base = blockIdx.x * CHUNK;
    const int nedge = min(CHUNK, N_EDGES - base);

    for (int k = t; k < NBKT; k += 256) hcnt[k] = 0;
    __syncthreads();

    int w0[16], w1[16], rk[16];
    #pragma unroll
    for (int j = 0; j < 16; ++j) {
        const int i = j * 256 + t;            // coalesced per j
        rk[j] = -1;
        if (i < nedge) {
            const int e = base + i;
            const int r = er[e];
            const int bk = r >> 7;
            w0[j] = ec[e] | ((r & 127) << 16) | (bk << 23);
            w1[j] = __float_as_int(ev[e]);
            rk[j] = atomicAdd(&hcnt[bk], 1);
        }
    }
    __syncthreads();

    sc[t]       = (t < NBKT) ? hcnt[t] : 0;
    sc[t + 256] = (t + 256 < NBKT) ? hcnt[t + 256] : 0;
    __syncthreads();
    #pragma unroll
    for (int off = 1; off < 512; off <<= 1) {
        const int a0 = (t >= off) ? sc[t - off] : 0;
        const int a1 = sc[t + 256 - off];
        __syncthreads();
        sc[t] += a0;
        sc[t + 256] += a1;
        __syncthreads();
    }
    if (t < NBKT)       loff[t]       = sc[t] - hcnt[t];
    if (t + 256 < NBKT) loff[t + 256] = sc[t + 256] - hcnt[t + 256];

    if (t < NBKT && hcnt[t] > 0)
        gbase[t] = t * CAP + atomicAdd(&cursor[t], hcnt[t]);
    if (t + 256 < NBKT && hcnt[t + 256] > 0)
        gbase[t + 256] = (t + 256) * CAP + atomicAdd(&cursor[t + 256], hcnt[t + 256]);
    __syncthreads();

    #pragma unroll
    for (int j = 0; j < 16; ++j) {
        if (rk[j] >= 0) {
            const int bk = ((u32)w0[j]) >> 23;
            const int s = loff[bk] + rk[j];
            estage[s] = make_int2(w0[j], w1[j]);
            bslot[s]  = (u16)bk;
        }
    }
    __syncthreads();

    for (int s = t; s < nedge; s += 256) {
        const int bk = bslot[s];
        const int2 e2 = estage[s];
        const int gpos = gbase[bk] + (s - loff[bk]);
        if (gpos < (bk + 1) * CAP)            // overflow guard (never in practice)
            tmp[gpos] = e2;
    }
}

// per bucket: inline 391-scan of bucket counts, then LDS row-hist + scan ->
// row_ptr, scatter into 32KB L2-resident window with LDS cursors.
__global__ __launch_bounds__(256) void scatter2(const int* __restrict__ cursor,
                                                const int2* __restrict__ tmp,
                                                int* __restrict__ row_ptr,
                                                int2* __restrict__ sedge) {
    __shared__ int sc[512];
    __shared__ int orig[512];
    __shared__ int rcnt[RPB];
    __shared__ int rsc[RPB];
    __shared__ int rcur[RPB];
    const int t = threadIdx.x;
    const int b = blockIdx.x;

    // global exclusive scan of min(cursor[i], CAP) over all 391 buckets
    const int c0 = (t < NBKT) ? min(cursor[t], CAP) : 0;
    const int c1 = (t + 256 < NBKT) ? min(cursor[t + 256], CAP) : 0;
    sc[t] = c0;       orig[t] = c0;
    sc[t + 256] = c1; orig[t + 256] = c1;
    __syncthreads();
    #pragma unroll
    for (int off = 1; off < 512; off <<= 1) {
        const int a0 = (t >= off) ? sc[t - off] : 0;
        const int a1 = sc[t + 256 - off];
        __syncthreads();
        sc[t] += a0;
        sc[t + 256] += a1;
        __syncthreads();
    }
    const int gb = sc[b] - orig[b];           // exclusive prefix at bucket b
    const int n  = orig[b];                   // this bucket's edge count
    const int2* src = tmp + (size_t)b * CAP;

    if (b == 0 && t == 0) row_ptr[N_NODES] = N_EDGES;

    if (t < RPB) rcnt[t] = 0;
    __syncthreads();
    for (int i = t; i < n; i += 256)
        atomicAdd(&rcnt[(((u32)src[i].x) >> 16) & 127], 1);
    __syncthreads();

    if (t < RPB) rsc[t] = rcnt[t];
    __syncthreads();
    #pragma unroll
    for (int off = 1; off < RPB; off <<= 1) {
        int a = 0;
        if (t < RPB && t >= off) a = rsc[t - off];
        __syncthreads();
        if (t < RPB) rsc[t] += a;
        __syncthreads();
    }
    if (t < RPB) {
        const int excl = rsc[t] - rcnt[t];
        rcur[t] = gb + excl;
        const int row = b * RPB + t;
        if (row < N_NODES) row_ptr[row] = gb + excl;
    }
    __syncthreads();

    for (int i = t; i < n; i += 256) {
        const int2 e2 = src[i];                       // L2-hot (2nd pass)
        const int rloc = (((u32)e2.x) >> 16) & 127;
        const int pos = atomicAdd(&rcur[rloc], 1);    // LDS atomic
        sedge[pos] = make_int2(e2.x & 0xFFFF, e2.y);  // within 32KB window
    }
}

// ---------------------------------------------------------------------------
// W [512,256] fp32  ->  WT [256,512] bf16 (transposed, K-contiguous)
// ---------------------------------------------------------------------------
__global__ __launch_bounds__(256) void wcvt(const float* __restrict__ W,
                                            u16* __restrict__ WT) {
    const int n  = threadIdx.x;
    const int k0 = blockIdx.x * 4;
    ushort4 o;
    o.x = f_to_bf(W[(size_t)(k0 + 0) * OUT_DIM + n]);
    o.y = f_to_bf(W[(size_t)(k0 + 1) * OUT_DIM + n]);
    o.z = f_to_bf(W[(size_t)(k0 + 2) * OUT_DIM + n]);
    o.w = f_to_bf(W[(size_t)(k0 + 3) * OUT_DIM + n]);
    *(ushort4*)(WT + (size_t)n * IN_DIM + k0) = o;
}

// ---------------------------------------------------------------------------
// GEMM: Sbc[chunk][M][32] = bf16( X[M,512] @ W[512,256] ), MFMA 16x16x32.
// 64x256 tile (X read once, 782 blocks = 3.05/CU balanced); epilogue writes
// chunk-major (verified in round-2) so each 32-ch slice is contiguous 3.2MB.
// ---------------------------------------------------------------------------
__global__ __launch_bounds__(256) void gemm_mfma(const float* __restrict__ X,
                                                 const u16* __restrict__ WT,
                                                 u16* __restrict__ Sbc) {
    __shared__ u16 As[BM * LDA];   //  5,120 B
    __shared__ u16 Bs[BN * LDA];   // 20,480 B

    const int tid  = threadIdx.x;
    const int wave = tid >> 6;          // 0..3
    const int lane = tid & 63;
    const int r0   = blockIdx.x * BM;
    const int wn   = wave * 64;         // 0,64,128,192
    const int l15  = lane & 15;
    const int quad = lane >> 4;

    f32x4 acc[4][4];
    #pragma unroll
    for (int i = 0; i < 4; ++i)
        #pragma unroll
        for (int j = 0; j < 4; ++j) acc[i][j] = (f32x4)0.f;

    // A-staging: 64 rows x 32 k / 256 thr -> 4 thr/row, 8 k each
    const int arow = tid >> 2;
    const int akp  = (tid & 3) * 8;
    const int xrow = min(r0 + arow, N_NODES - 1); // clamp; stores masked
    const float* xsrc = X + (size_t)xrow * IN_DIM + akp;
    // B-staging: 256 rows x 32 k / 256 thr -> 2 thr/row, 16 k, 2 row-halves
    const int brow = tid >> 1;
    const int bkp  = (tid & 1) * 16;
    const u16* bsrc = WT + (size_t)brow * IN_DIM + bkp;

    for (int kc = 0; kc < IN_DIM; kc += BK) {
        {   // A: 8 fp32 -> 8 bf16
            const float4 f0 = *(const float4*)(xsrc + kc + 0);
            const float4 f1 = *(const float4*)(xsrc + kc + 4);
            ushort4 p0, p1;
            p0.x = f_to_bf(f0.x); p0.y = f_to_bf(f0.y); p0.z = f_to_bf(f0.z); p0.w = f_to_bf(f0.w);
            p1.x = f_to_bf(f1.x); p1.y = f_to_bf(f1.y); p1.z = f_to_bf(f1.z); p1.w = f_to_bf(f1.w);
            *(ushort4*)&As[arow * LDA + akp + 0] = p0;
            *(ushort4*)&As[arow * LDA + akp + 4] = p1;
        }
        {   // B: two row-halves, 16 bf16 each
            const uint4 b0 = *(const uint4*)(bsrc + kc);
            const uint4 b1 = *(const uint4*)(bsrc + kc + 8);
            *(uint4*)&Bs[brow * LDA + bkp + 0] = b0;
            *(uint4*)&Bs[brow * LDA + bkp + 8] = b1;
            const u16* bsrc2 = bsrc + (size_t)128 * IN_DIM;
            const uint4 b2 = *(const uint4*)(bsrc2 + kc);
            const uint4 b3 = *(const uint4*)(bsrc2 + kc + 8);
            *(uint4*)&Bs[(brow + 128) * LDA + bkp + 0] = b2;
            *(uint4*)&Bs[(brow + 128) * LDA + bkp + 8] = b3;
        }
        __syncthreads();

        bf16x8 af[4], bfr[4];
        #pragma unroll
        for (int mt = 0; mt < 4; ++mt)
            af[mt] = *(const bf16x8*)&As[(mt * 16 + l15) * LDA + quad * 8];
        #pragma unroll
        for (int nt = 0; nt < 4; ++nt)
            bfr[nt] = *(const bf16x8*)&Bs[(wn + nt * 16 + l15) * LDA + quad * 8];
        #pragma unroll
        for (int mt = 0; mt < 4; ++mt)
            #pragma unroll
            for (int nt = 0; nt < 4; ++nt)
                acc[mt][nt] = __builtin_amdgcn_mfma_f32_16x16x32_bf16(
                    af[mt], bfr[nt], acc[mt][nt], 0, 0, 0);
        __syncthreads();
    }

    // epilogue, chunk-major: Sbc[(col>>5)][grow][col&31]
    #pragma unroll
    for (int mt = 0; mt < 4; ++mt) {
        #pragma unroll
        for (int r = 0; r < 4; ++r) {
            const int grow = r0 + mt * 16 + quad * 4 + r;
            if (grow < N_NODES) {
                #pragma unroll
                for (int nt = 0; nt < 4; ++nt) {
                    const int col = wn + nt * 16 + l15;
                    Sbc[((size_t)(col >> 5) * N_NODES + grow) * 32 + (col & 31)]
                        = f_to_bf(acc[mt][nt][r]);
                }
            }
        }
    }
}

// ---------------------------------------------------------------------------
// spmm_c8: out[r, chunk*32..+32) = bias + sum val * Sbc[chunk][col]
// Combines round-2's VERIFIED locality (chunk = bid&7 -> XCD pin, 3.2MB
// L2-resident slice, FETCH 351->112MB) with round-1's instruction economy:
// lane = (edge-slot l>>3, channel-quad l&7), so ONE gather instruction
// covers 8 edges x 32 ch = 512 B (round-2 did 1 edge = 64 B -> 3x VALU blowup).
// 4 batches unrolled = 32 edges = 4 gathers in flight.  Row-end: 3x shfl_xor
// folds the 8 edge slots; slot-0 lanes store contiguous 128 B + bias.
// ---------------------------------------------------------------------------
__global__ __launch_bounds__(256) void spmm_c8(const int* __restrict__ row_ptr,
                                               const int2* __restrict__ sedge,
                                               const u16* __restrict__ Sbc,
                                               const float* __restrict__ bias,
                                               float* __restrict__ out) {
    const int bid   = blockIdx.x;
    const int chunk = bid & 7;               // XCD pin (round-robin dispatch)
    const int rg    = bid >> 3;              // 0..12499
    const int wave  = threadIdx.x >> 6;
    const int lane  = threadIdx.x & 63;
    const int slot  = lane >> 3;             // 0..7: edge slot
    const int sub   = lane & 7;              // 0..7: channel quad
    const int r     = rg * 4 + wave;         // 50000 = 12500*4 exact

    const int start = row_ptr[r];
    const int end   = row_ptr[r + 1];

    const u16* sb = Sbc + (size_t)chunk * ((size_t)N_NODES * 32) + sub * 4;
    float4 acc = make_float4(0.f, 0.f, 0.f, 0.f);

    for (int e = start; e < end; e += 32) {
        int   cols[4];
        float vals[4];
        #pragma unroll
        for (int u = 0; u < 4; ++u) {
            const int idx = e + u * 8 + slot;
            const int2 ed = sedge[min(idx, end - 1)];   // clamp: row nonempty here
            cols[u] = ed.x;
            vals[u] = (idx < end) ? __int_as_float(ed.y) : 0.f;
        }
        ushort4 sv[4];
        #pragma unroll
        for (int u = 0; u < 4; ++u)
            sv[u] = *(const ushort4*)(sb + (size_t)cols[u] * 32);
        #pragma unroll
        for (int u = 0; u < 4; ++u) {
            acc.x += vals[u] * bf_to_f(sv[u].x);
            acc.y += vals[u] * bf_to_f(sv[u].y);
            acc.z += vals[u] * bf_to_f(sv[u].z);
            acc.w += vals[u] * bf_to_f(sv[u].w);
        }
    }

    // fold the 8 edge slots (lane bits 3,4,5)
    #pragma unroll
    for (int m = 8; m <= 32; m <<= 1) {
        acc.x += __shfl_xor(acc.x, m);
        acc.y += __shfl_xor(acc.y, m);
        acc.z += __shfl_xor(acc.z, m);
        acc.w += __shfl_xor(acc.w, m);
    }
    if (slot == 0) {
        const float4 b4 = *(const float4*)(bias + chunk * 32 + sub * 4);
        float4 o;
        o.x = acc.x + b4.x; o.y = acc.y + b4.y;
        o.z = acc.z + b4.z; o.w = acc.w + b4.w;
        *(float4*)(out + (size_t)r * OUT_DIM + chunk * 32 + sub * 4) = o;
    }
}

extern "C" void kernel_launch(void* const* d_in, const int* in_sizes, int n_in,
                              void* d_out, int out_size, void* d_ws, size_t ws_size,
                              hipStream_t stream) {
    const float* X    = (const float*)d_in[0];
    const int*   er   = (const int*)d_in[1];
    const int*   ec   = (const int*)d_in[2];
    const float* ev   = (const float*)d_in[3];
    const float* W    = (const float*)d_in[4];
    const float* bias = (const float*)d_in[5];
    float* out        = (float*)d_out;

    // ws layout (~38.9 MB).  tmp/cursor alias the Sbc region: they are dead
    // before gemm_mfma writes Sbc (stream-ordered).
    char* ws = (char*)d_ws;
    u16*  Sbc     = (u16*) (ws);                       // 25,600,000 B
    int2* tmp     = (int2*)(ws);                       // 16,015,360 B (alias)
    int*  cursor  = (int*) (ws + 16100000);            //      1,564 B (alias)
    int2* sedge   = (int2*)(ws + 25600000);            // 12,800,000 B
    u16*  WT      = (u16*) (ws + 38400000);            //    262,144 B
    int*  row_ptr = (int*) (ws + 38662144);            //    200,004 B

    hipLaunchKernelGGL(zero_cur, dim3(2), dim3(256), 0, stream, cursor);
    hipLaunchKernelGGL(scatter1, dim3((N_EDGES + CHUNK - 1) / CHUNK), dim3(256), 0,
                       stream, er, ec, ev, cursor, tmp);
    hipLaunchKernelGGL(scatter2, dim3(NBKT), dim3(256), 0, stream,
                       cursor, tmp, row_ptr, sedge);
    hipLaunchKernelGGL(wcvt, dim3(IN_DIM / 4), dim3(256), 0, stream, W, WT);
    hipLaunchKernelGGL(gemm_mfma, dim3((N_NODES + BM - 1) / BM), dim3(256), 0,
                       stream, X, WT, Sbc);
    hipLaunchKernelGGL(spmm_c8, dim3(8 * (N_NODES / 4)), dim3(256), 0, stream,
                       row_ptr, sedge, Sbc, bias, out);
}

// Round 8
// 356.601 us; speedup vs baseline: 1.1535x; 1.1535x over previous
//
#include <hip/hip_runtime.h>

#define N_NODES 50000
#define N_EDGES 1600000
#define IN_DIM 512
#define OUT_DIM 256

#define BM 64                  // 782 blocks = 3.05/CU (balanced); X read once (BN=256)
#define BN 256
#define BK 32
#define APAD 8                 // pad rows to 40 shorts = 80 B -> 2-way banks (free)
#define LDA (BK + APAD)

// ---- two-level counting sort geometry ----
#define RPB   128              // rows per bucket (rloc = 7 bits)
#define NBKT  391              // ceil(50000 / 128)
#define CHUNK 4096             // edges per scatter1 block
#define CAP   5120             // per-bucket tmp capacity (mean 4096, sigma 64 -> +16 sigma)

typedef unsigned int u32;
typedef unsigned short u16;
typedef short bf16x8 __attribute__((ext_vector_type(8)));
typedef float f32x4 __attribute__((ext_vector_type(4)));

__device__ __forceinline__ float bf_to_f(u16 u) { return __uint_as_float(((u32)u) << 16); }
__device__ __forceinline__ u16 f_to_bf(float f) {
    u32 u = __float_as_uint(f);
    u32 r = (u + 0x7fffu + ((u >> 16) & 1u)) >> 16;   // RNE
    return (u16)r;
}

// ---------------------------------------------------------------------------
// CSR build, two-level (verified round-1/5 structure).
// ---------------------------------------------------------------------------

// edges -> bucket-major tmp (fixed CAP per bucket).  Edge packed as
// w0 = col | (rloc<<16) | (bkt<<23), w1 = val bits (col < 65536, rloc < 128).
__global__ __launch_bounds__(256) void scatter1(const int* __restrict__ er,
                                                const int* __restrict__ ec,
                                                const float* __restrict__ ev,
                                                int* __restrict__ cursor,
                                                int2* __restrict__ tmp) {
    __shared__ int  hcnt[NBKT];
    __shared__ int  loff[NBKT];
    __shared__ int  gbase[NBKT];
    __shared__ int  sc[512];
    __shared__ int2 estage[CHUNK];   // 32 KB
    __shared__ u16  bslot[CHUNK];    // 8 KB

    const int t = threadIdx.x;
    const int base = blockIdx.x * CHUNK;
    const int nedge = min(CHUNK, N_EDGES - base);

    for (int k = t; k < NBKT; k += 256) hcnt[k] = 0;
    __syncthreads();

    int w0[16], w1[16], rk[16];
    #pragma unroll
    for (int j = 0; j < 16; ++j) {
        const int i = j * 256 + t;            // coalesced per j
        rk[j] = -1;
        if (i < nedge) {
            const int e = base + i;
            const int r = er[e];
            const int bk = r >> 7;
            w0[j] = ec[e] | ((r & 127) << 16) | (bk << 23);
            w1[j] = __float_as_int(ev[e]);
            rk[j] = atomicAdd(&hcnt[bk], 1);
        }
    }
    __syncthreads();

    sc[t]       = (t < NBKT) ? hcnt[t] : 0;
    sc[t + 256] = (t + 256 < NBKT) ? hcnt[t + 256] : 0;
    __syncthreads();
    #pragma unroll
    for (int off = 1; off < 512; off <<= 1) {
        const int a0 = (t >= off) ? sc[t - off] : 0;
        const int a1 = sc[t + 256 - off];
        __syncthreads();
        sc[t] += a0;
        sc[t + 256] += a1;
        __syncthreads();
    }
    if (t < NBKT)       loff[t]       = sc[t] - hcnt[t];
    if (t + 256 < NBKT) loff[t + 256] = sc[t + 256] - hcnt[t + 256];

    if (t < NBKT && hcnt[t] > 0)
        gbase[t] = t * CAP + atomicAdd(&cursor[t], hcnt[t]);
    if (t + 256 < NBKT && hcnt[t + 256] > 0)
        gbase[t + 256] = (t + 256) * CAP + atomicAdd(&cursor[t + 256], hcnt[t + 256]);
    __syncthreads();

    #pragma unroll
    for (int j = 0; j < 16; ++j) {
        if (rk[j] >= 0) {
            const int bk = ((u32)w0[j]) >> 23;
            const int s = loff[bk] + rk[j];
            estage[s] = make_int2(w0[j], w1[j]);
            bslot[s]  = (u16)bk;
        }
    }
    __syncthreads();

    for (int s = t; s < nedge; s += 256) {
        const int bk = bslot[s];
        const int2 e2 = estage[s];
        const int gpos = gbase[bk] + (s - loff[bk]);
        if (gpos < (bk + 1) * CAP)            // overflow guard (never in practice)
            tmp[gpos] = e2;
    }
}

// per bucket: inline 391-scan of bucket counts, then LDS row-hist + scan ->
// row_ptr, scatter into 32KB L2-resident window with LDS cursors.
__global__ __launch_bounds__(256) void scatter2(const int* __restrict__ cursor,
                                                const int2* __restrict__ tmp,
                                                int* __restrict__ row_ptr,
                                                int2* __restrict__ sedge) {
    __shared__ int sc[512];
    __shared__ int orig[512];
    __shared__ int rcnt[RPB];
    __shared__ int rsc[RPB];
    __shared__ int rcur[RPB];
    const int t = threadIdx.x;
    const int b = blockIdx.x;

    // global exclusive scan of min(cursor[i], CAP) over all 391 buckets
    const int c0 = (t < NBKT) ? min(cursor[t], CAP) : 0;
    const int c1 = (t + 256 < NBKT) ? min(cursor[t + 256], CAP) : 0;
    sc[t] = c0;       orig[t] = c0;
    sc[t + 256] = c1; orig[t + 256] = c1;
    __syncthreads();
    #pragma unroll
    for (int off = 1; off < 512; off <<= 1) {
        const int a0 = (t >= off) ? sc[t - off] : 0;
        const int a1 = sc[t + 256 - off];
        __syncthreads();
        sc[t] += a0;
        sc[t + 256] += a1;
        __syncthreads();
    }
    const int gb = sc[b] - orig[b];           // exclusive prefix at bucket b
    const int n  = orig[b];                   // this bucket's edge count
    const int2* src = tmp + (size_t)b * CAP;

    if (b == 0 && t == 0) row_ptr[N_NODES] = N_EDGES;

    if (t < RPB) rcnt[t] = 0;
    __syncthreads();
    for (int i = t; i < n; i += 256)
        atomicAdd(&rcnt[(((u32)src[i].x) >> 16) & 127], 1);
    __syncthreads();

    if (t < RPB) rsc[t] = rcnt[t];
    __syncthreads();
    #pragma unroll
    for (int off = 1; off < RPB; off <<= 1) {
        int a = 0;
        if (t < RPB && t >= off) a = rsc[t - off];
        __syncthreads();
        if (t < RPB) rsc[t] += a;
        __syncthreads();
    }
    if (t < RPB) {
        const int excl = rsc[t] - rcnt[t];
        rcur[t] = gb + excl;
        const int row = b * RPB + t;
        if (row < N_NODES) row_ptr[row] = gb + excl;
    }
    __syncthreads();

    for (int i = t; i < n; i += 256) {
        const int2 e2 = src[i];                       // L2-hot (2nd pass)
        const int rloc = (((u32)e2.x) >> 16) & 127;
        const int pos = atomicAdd(&rcur[rloc], 1);    // LDS atomic
        sedge[pos] = make_int2(e2.x & 0xFFFF, e2.y);  // within 32KB window
    }
}

// ---------------------------------------------------------------------------
// W [512,256] fp32 -> WT [256,512] bf16 (transposed, K-contiguous).
// Also zeroes cursor[] (folded zero_cur: one fewer launch+drain; runs first).
// ---------------------------------------------------------------------------
__global__ __launch_bounds__(256) void wcvt_zero(const float* __restrict__ W,
                                                 u16* __restrict__ WT,
                                                 int* __restrict__ cursor) {
    if (blockIdx.x < 2) {
        const int i = blockIdx.x * 256 + threadIdx.x;
        if (i < NBKT) cursor[i] = 0;
    }
    const int n  = threadIdx.x;
    const int k0 = blockIdx.x * 4;
    ushort4 o;
    o.x = f_to_bf(W[(size_t)(k0 + 0) * OUT_DIM + n]);
    o.y = f_to_bf(W[(size_t)(k0 + 1) * OUT_DIM + n]);
    o.z = f_to_bf(W[(size_t)(k0 + 2) * OUT_DIM + n]);
    o.w = f_to_bf(W[(size_t)(k0 + 3) * OUT_DIM + n]);
    *(ushort4*)(WT + (size_t)n * IN_DIM + k0) = o;
}

// ---------------------------------------------------------------------------
// GEMM: Sb[M,256] = bf16( X[M,512] @ W[512,256] ), MFMA 16x16x32.
// 64x256 tile (X read once, 782 blocks = 3.05/CU balanced); row-major Sb.
// ---------------------------------------------------------------------------
__global__ __launch_bounds__(256) void gemm_mfma(const float* __restrict__ X,
                                                 const u16* __restrict__ WT,
                                                 u16* __restrict__ Sb) {
    __shared__ u16 As[BM * LDA];   //  5,120 B
    __shared__ u16 Bs[BN * LDA];   // 20,480 B

    const int tid  = threadIdx.x;
    const int wave = tid >> 6;          // 0..3
    const int lane = tid & 63;
    const int r0   = blockIdx.x * BM;
    const int wn   = wave * 64;         // 0,64,128,192
    const int l15  = lane & 15;
    const int quad = lane >> 4;

    f32x4 acc[4][4];
    #pragma unroll
    for (int i = 0; i < 4; ++i)
        #pragma unroll
        for (int j = 0; j < 4; ++j) acc[i][j] = (f32x4)0.f;

    // A-staging: 64 rows x 32 k / 256 thr -> 4 thr/row, 8 k each
    const int arow = tid >> 2;
    const int akp  = (tid & 3) * 8;
    const int xrow = min(r0 + arow, N_NODES - 1); // clamp; stores masked
    const float* xsrc = X + (size_t)xrow * IN_DIM + akp;
    // B-staging: 256 rows x 32 k / 256 thr -> 2 thr/row, 16 k, 2 row-halves
    const int brow = tid >> 1;
    const int bkp  = (tid & 1) * 16;
    const u16* bsrc = WT + (size_t)brow * IN_DIM + bkp;

    for (int kc = 0; kc < IN_DIM; kc += BK) {
        {   // A: 8 fp32 -> 8 bf16
            const float4 f0 = *(const float4*)(xsrc + kc + 0);
            const float4 f1 = *(const float4*)(xsrc + kc + 4);
            ushort4 p0, p1;
            p0.x = f_to_bf(f0.x); p0.y = f_to_bf(f0.y); p0.z = f_to_bf(f0.z); p0.w = f_to_bf(f0.w);
            p1.x = f_to_bf(f1.x); p1.y = f_to_bf(f1.y); p1.z = f_to_bf(f1.z); p1.w = f_to_bf(f1.w);
            *(ushort4*)&As[arow * LDA + akp + 0] = p0;
            *(ushort4*)&As[arow * LDA + akp + 4] = p1;
        }
        {   // B: two row-halves, 16 bf16 each
            const uint4 b0 = *(const uint4*)(bsrc + kc);
            const uint4 b1 = *(const uint4*)(bsrc + kc + 8);
            *(uint4*)&Bs[brow * LDA + bkp + 0] = b0;
            *(uint4*)&Bs[brow * LDA + bkp + 8] = b1;
            const u16* bsrc2 = bsrc + (size_t)128 * IN_DIM;
            const uint4 b2 = *(const uint4*)(bsrc2 + kc);
            const uint4 b3 = *(const uint4*)(bsrc2 + kc + 8);
            *(uint4*)&Bs[(brow + 128) * LDA + bkp + 0] = b2;
            *(uint4*)&Bs[(brow + 128) * LDA + bkp + 8] = b3;
        }
        __syncthreads();

        bf16x8 af[4], bfr[4];
        #pragma unroll
        for (int mt = 0; mt < 4; ++mt)
            af[mt] = *(const bf16x8*)&As[(mt * 16 + l15) * LDA + quad * 8];
        #pragma unroll
        for (int nt = 0; nt < 4; ++nt)
            bfr[nt] = *(const bf16x8*)&Bs[(wn + nt * 16 + l15) * LDA + quad * 8];
        #pragma unroll
        for (int mt = 0; mt < 4; ++mt)
            #pragma unroll
            for (int nt = 0; nt < 4; ++nt)
                acc[mt][nt] = __builtin_amdgcn_mfma_f32_16x16x32_bf16(
                    af[mt], bfr[nt], acc[mt][nt], 0, 0, 0);
        __syncthreads();
    }

    // epilogue: D[row = quad*4 + r][col = l15] per 16x16 tile; Sb row-major
    #pragma unroll
    for (int mt = 0; mt < 4; ++mt) {
        #pragma unroll
        for (int r = 0; r < 4; ++r) {
            const int grow = r0 + mt * 16 + quad * 4 + r;
            if (grow < N_NODES) {
                u16* dst = Sb + (size_t)grow * OUT_DIM + wn + l15;
                #pragma unroll
                for (int nt = 0; nt < 4; ++nt)
                    dst[nt * 16] = f_to_bf(acc[mt][nt][r]);
            }
        }
    }
}

// ---------------------------------------------------------------------------
// out[r] = bias + sum_{e in row r} val[e] * Sb[col[e]]
// Round-1 verified addressing (wave = row, lane = 4 ch, 512B/gather), with
// the ILP deepened 8 -> 16 outstanding gathers (theory: concurrency x
// latency bound at 3 TB/s effective; 8 in flight was the cap).  Main loop
// takes full clamp-free 16-batches; ONE clamped tail batch handles the rest
// (removes 2 VALU ops/edge from the hot path).
// (Round-6 chunked variant: FETCH 351->84MB but VALU 2x -> 182us. Abandoned.)
// ---------------------------------------------------------------------------
__global__ __launch_bounds__(256) void csr_spmm(const int* __restrict__ row_ptr,
                                                const int2* __restrict__ sedge,
                                                const u16* __restrict__ Sb,
                                                const float* __restrict__ bias,
                                                float* __restrict__ out) {
    const int wave = threadIdx.x >> 6;
    const int lane = threadIdx.x & 63;
    const int r = blockIdx.x * 4 + wave;
    if (r >= N_NODES) return;

    const int start = row_ptr[r];
    const int end   = row_ptr[r + 1];

    float4 acc = *(const float4*)(bias + lane * 4);
    const u16* sbase = Sb + lane * 4;

    int e = start;
    // main: full 16-edge batches, no clamping, 16 gathers in flight
    for (; e + 16 <= end; e += 16) {
        int2 ed[16];
        #pragma unroll
        for (int j = 0; j < 16; ++j) ed[j] = sedge[e + j];

        ushort4 sv[16];
        #pragma unroll
        for (int j = 0; j < 16; ++j)
            sv[j] = *(const ushort4*)(sbase + (size_t)ed[j].x * OUT_DIM);

        #pragma unroll
        for (int j = 0; j < 16; ++j) {
            const float vj = __int_as_float(ed[j].y);
            acc.x += vj * bf_to_f(sv[j].x);
            acc.y += vj * bf_to_f(sv[j].y);
            acc.z += vj * bf_to_f(sv[j].z);
            acc.w += vj * bf_to_f(sv[j].w);
        }
    }
    // tail: one clamped batch (row nonempty here since e < end)
    if (e < end) {
        int2 ed[16];
        #pragma unroll
        for (int j = 0; j < 16; ++j)
            ed[j] = sedge[min(e + j, end - 1)];
        #pragma unroll
        for (int j = 0; j < 16; ++j)
            if (e + j >= end) ed[j].y = 0;            // 0.0f bits on padding

        ushort4 sv[16];
        #pragma unroll
        for (int j = 0; j < 16; ++j)
            sv[j] = *(const ushort4*)(sbase + (size_t)ed[j].x * OUT_DIM);

        #pragma unroll
        for (int j = 0; j < 16; ++j) {
            const float vj = __int_as_float(ed[j].y);
            acc.x += vj * bf_to_f(sv[j].x);
            acc.y += vj * bf_to_f(sv[j].y);
            acc.z += vj * bf_to_f(sv[j].z);
            acc.w += vj * bf_to_f(sv[j].w);
        }
    }

    *(float4*)(out + (size_t)r * OUT_DIM + lane * 4) = acc;
}

extern "C" void kernel_launch(void* const* d_in, const int* in_sizes, int n_in,
                              void* d_out, int out_size, void* d_ws, size_t ws_size,
                              hipStream_t stream) {
    const float* X    = (const float*)d_in[0];
    const int*   er   = (const int*)d_in[1];
    const int*   ec   = (const int*)d_in[2];
    const float* ev   = (const float*)d_in[3];
    const float* W    = (const float*)d_in[4];
    const float* bias = (const float*)d_in[5];
    float* out        = (float*)d_out;

    // ws layout (~38.9 MB).  tmp/cursor alias the Sb region: they are dead
    // before gemm_mfma writes Sb (stream-ordered).
    char* ws = (char*)d_ws;
    u16*  Sb      = (u16*) (ws);                       // 25,600,000 B
    int2* tmp     = (int2*)(ws);                       // 16,015,360 B (alias)
    int*  cursor  = (int*) (ws + 16100000);            //      1,564 B (alias)
    int2* sedge   = (int2*)(ws + 25600000);            // 12,800,000 B
    u16*  WT      = (u16*) (ws + 38400000);            //    262,144 B
    int*  row_ptr = (int*) (ws + 38662144);            //    200,004 B

    hipLaunchKernelGGL(wcvt_zero, dim3(IN_DIM / 4), dim3(256), 0, stream,
                       W, WT, cursor);
    hipLaunchKernelGGL(scatter1, dim3((N_EDGES + CHUNK - 1) / CHUNK), dim3(256), 0,
                       stream, er, ec, ev, cursor, tmp);
    hipLaunchKernelGGL(scatter2, dim3(NBKT), dim3(256), 0, stream,
                       cursor, tmp, row_ptr, sedge);
    hipLaunchKernelGGL(gemm_mfma, dim3((N_NODES + BM - 1) / BM), dim3(256), 0,
                       stream, X, WT, Sb);
    hipLaunchKernelGGL(csr_spmm, dim3((N_NODES + 3) / 4), dim3(256), 0, stream,
                       row_ptr, sedge, Sb, bias, out);
}